// Round 6
// baseline (796.283 us; speedup 1.0000x reference)
//
#include <hip/hip_runtime.h>
#include <stdint.h>

#define NUM_CHARS 128
#define BATCH 8192
#define SEQ 40
#define HIDDEN 256
#define ZDIM 1024   /* 4*HIDDEN */
#define SH 264      /* padded h row stride in ushorts */
/* 256 threads = 4 waves, 1 wave/SIMD -> 512 unified regs/lane.
   Wave v owns hcols [64v,64v+64): ntiles NT(g,p)=g*8+2v+p, 8 accumulators.
   Wh kk partition: kk 0..3 LDS (128 KB), kk 4..7 register-resident (128 VGPRs/lane),
   kk 8..15 streamed from L2 (2-deep window, 64 VGPRs). */

typedef __bf16 bf16x8 __attribute__((ext_vector_type(8)));
typedef float floatx16 __attribute__((ext_vector_type(16)));

__device__ __forceinline__ unsigned short f2bf(float f) {
    union { float f; uint32_t u; } v; v.f = f;
    uint32_t u = v.u;
    u += 0x7FFFu + ((u >> 16) & 1u); // RNE
    return (unsigned short)(u >> 16);
}

// WhFrag[ntile(32)][kk(16)][lane(64)][j(8)] bf16 ; element = Wh[k][n],
// k = kk*16 + (lane>>5)*8 + j, n = ntile*32 + (lane&31)
__global__ void prep_wh(const float* __restrict__ Wh, unsigned short* __restrict__ out) {
    int idx = blockIdx.x * blockDim.x + threadIdx.x; // 0..262143
    int j = idx & 7;
    int lane = (idx >> 3) & 63;
    int kk = (idx >> 9) & 15;
    int ntile = idx >> 13;
    int k = kk * 16 + ((lane >> 5) << 3) + j;
    int n = (ntile << 5) + (lane & 31);
    out[idx] = f2bf(Wh[k * ZDIM + n]);
}

// WxbG[vocab(128)][n(256)][g(4)] bf16 = Wx + b, gate-interleaved: one uint2 = 4 gates
__global__ void prep_wxb4(const float* __restrict__ Wx, const float* __restrict__ b,
                          unsigned short* __restrict__ out) {
    int idx = blockIdx.x * blockDim.x + threadIdx.x; // 0..131071
    int v = idx >> 10;
    int n = (idx >> 2) & 255;
    int g = idx & 3;
    out[idx] = f2bf(Wx[v * ZDIM + g * 256 + n] + b[g * 256 + n]);
}

// WdFrag[ntile(4)][kk(16)][lane(64)][j(8)] bf16 ; element = Wd[k][n]
__global__ void prep_wd(const float* __restrict__ Wd, unsigned short* __restrict__ out) {
    int idx = blockIdx.x * blockDim.x + threadIdx.x; // 0..32767
    int j = idx & 7;
    int lane = (idx >> 3) & 63;
    int kk = (idx >> 9) & 15;
    int nt = idx >> 13;
    int k = kk * 16 + ((lane >> 5) << 3) + j;
    int n = (nt << 5) + (lane & 31);
    out[idx] = f2bf(Wd[k * NUM_CHARS + n]);
}

__device__ __forceinline__ void gates2(floatx16 (&acc)[4][2], floatx16 (&c_st)[2],
                                       unsigned short* hb, int rbase, int hcol0) {
    const float L2E = 1.4426950408889634f;
#pragma unroll
    for (int p = 0; p < 2; ++p) {
#pragma unroll
        for (int i = 0; i < 16; ++i) {
            float zi = acc[0][p][i], zf = acc[1][p][i], zg = acc[2][p][i], zo = acc[3][p][i];
            float si = __builtin_amdgcn_rcpf(1.f + __builtin_amdgcn_exp2f(-zi * L2E));
            float sf = __builtin_amdgcn_rcpf(1.f + __builtin_amdgcn_exp2f(-zf * L2E));
            float so = __builtin_amdgcn_rcpf(1.f + __builtin_amdgcn_exp2f(-zo * L2E));
            float tg = 1.f - 2.f * __builtin_amdgcn_rcpf(1.f + __builtin_amdgcn_exp2f(2.f * L2E * zg));
            float c = sf * c_st[p][i] + si * tg;
            c_st[p][i] = c;
            float tc = 1.f - 2.f * __builtin_amdgcn_rcpf(1.f + __builtin_amdgcn_exp2f(2.f * L2E * c));
            hb[((i & 3) + 8 * (i >> 2) + rbase) * SH + hcol0 + 32 * p] = f2bf(so * tc);
        }
    }
}

// ---- main: 256 blocks x 256 threads; block owns 32 batch rows, 1 block/CU ----
__global__ __launch_bounds__(256, 1) void lstm_main(
    const int* __restrict__ inputs, const unsigned short* __restrict__ WhFrag,
    const unsigned short* __restrict__ WxbG, const unsigned short* __restrict__ WdFrag,
    const float* __restrict__ bd, float* __restrict__ out)
{
    __shared__ unsigned short wlds[32 * 4 * 512];     // 128 KB: kk 0..3, all 32 ntiles
    __shared__ unsigned short hbuf[32 * SH];          // 16.5 KB single h buffer
    __shared__ int tok[32 * SEQ];                     //  5.0 KB
    __shared__ float red[2][4][32];                   //  1.0 KB

    const int tid = threadIdx.x;
    const int v = tid >> 6;        // wave 0..3, owns hcols [64v, 64v+64)
    const int lane = tid & 63;
    const int r0 = blockIdx.x * 32;

    // stage tokens (coalesced)
    for (int i = tid; i < 32 * SEQ; i += 256) tok[i] = inputs[r0 * SEQ + i];
    // stage Wh kk 0..3 into LDS: 128 frags x 1KB; storage frag f = ntile*4 + kk
    for (int c = tid; c < 8192; c += 256) {
        int f = c >> 6, o = c & 63;
        *(bf16x8*)&wlds[(f << 9) + (o << 3)] =
            *(const bf16x8*)&WhFrag[((((f >> 2) << 4) + (f & 3)) << 9) + (o << 3)];
    }

    // register-resident kk 4..7 for this wave's 8 ntiles (128 VGPRs, loaded once)
    bf16x8 wr[4][2][4];
#pragma unroll
    for (int g = 0; g < 4; ++g)
#pragma unroll
        for (int p = 0; p < 2; ++p)
#pragma unroll
            for (int rk = 0; rk < 4; ++rk)
                wr[g][p][rk] = *(const bf16x8*)
                    &WhFrag[(((g * 8 + 2 * v + p) * 16 + 4 + rk) << 9) + (lane << 3)];

    const int hcol0 = (v << 6) + (lane & 31);
    const int hcol1 = hcol0 + 32;
    const int rbase = 4 * (lane >> 5);
    const int abase = (lane & 31) * SH + ((lane >> 5) << 3);

    floatx16 c_st[2];
#pragma unroll
    for (int p = 0; p < 2; ++p)
#pragma unroll
        for (int i = 0; i < 16; ++i) c_st[p][i] = 0.f;

    __syncthreads();  // tok + wlds ready

    uint2 xb[2][16];  // gather prefetch buffer (held across steps; 64 VGPRs)

    // ---- t = 0: h0 = 0, z = Wx[token]+b only ----
#pragma unroll
    for (int i = 0; i < 16; ++i) {
        int r = (i & 3) + 8 * (i >> 2) + rbase;
        int off = tok[r * SEQ] << 10;
        xb[0][i] = *(const uint2*)&WxbG[off + (hcol0 << 2)];
        xb[1][i] = *(const uint2*)&WxbG[off + (hcol1 << 2)];
    }
    {
        floatx16 acc[4][2];
#pragma unroll
        for (int p = 0; p < 2; ++p)
#pragma unroll
            for (int i = 0; i < 16; ++i) {
                uint32_t x = xb[p][i].x, y = xb[p][i].y;
                acc[0][p][i] = __uint_as_float(x << 16);
                acc[1][p][i] = __uint_as_float(x & 0xFFFF0000u);
                acc[2][p][i] = __uint_as_float(y << 16);
                acc[3][p][i] = __uint_as_float(y & 0xFFFF0000u);
            }
        // prefetch gather for t = 1
#pragma unroll
        for (int i = 0; i < 16; ++i) {
            int r = (i & 3) + 8 * (i >> 2) + rbase;
            int off = tok[r * SEQ + 1] << 10;
            xb[0][i] = *(const uint2*)&WxbG[off + (hcol0 << 2)];
            xb[1][i] = *(const uint2*)&WxbG[off + (hcol1 << 2)];
        }
        gates2(acc, c_st, hbuf, rbase, hcol0);
    }
    __syncthreads();

    // ---- t = 1..39 ----
#pragma unroll 1
    for (int t = 1; t < SEQ; ++t) {
        // preload stream window: kk 8,9 (slot = kk&1)
        bf16x8 sw[2][8];
#pragma unroll
        for (int s = 0; s < 2; ++s)
#pragma unroll
            for (int g = 0; g < 4; ++g)
#pragma unroll
                for (int p = 0; p < 2; ++p)
                    sw[s][2 * g + p] = *(const bf16x8*)
                        &WhFrag[(((g * 8 + 2 * v + p) * 16 + 8 + s) << 9) + (lane << 3)];

        // acc init from prefetched gather (xb regs die here)
        floatx16 acc[4][2];
#pragma unroll
        for (int p = 0; p < 2; ++p)
#pragma unroll
            for (int i = 0; i < 16; ++i) {
                uint32_t x = xb[p][i].x, y = xb[p][i].y;
                acc[0][p][i] = __uint_as_float(x << 16);
                acc[1][p][i] = __uint_as_float(x & 0xFFFF0000u);
                acc[2][p][i] = __uint_as_float(y << 16);
                acc[3][p][i] = __uint_as_float(y & 0xFFFF0000u);
            }
        // issue gather for t+1 (lands during MFMA + gates of this step)
        int tn = (t + 1 < SEQ) ? t + 1 : SEQ - 1;
#pragma unroll
        for (int i = 0; i < 16; ++i) {
            int r = (i & 3) + 8 * (i >> 2) + rbase;
            int off = tok[r * SEQ + tn] << 10;
            xb[0][i] = *(const uint2*)&WxbG[off + (hcol0 << 2)];
            xb[1][i] = *(const uint2*)&WxbG[off + (hcol1 << 2)];
        }

        // kk 0..3: B from LDS
#pragma unroll
        for (int kk = 0; kk < 4; ++kk) {
            bf16x8 af = *(const bf16x8*)&hbuf[abase + kk * 16];
#pragma unroll
            for (int g = 0; g < 4; ++g)
#pragma unroll
                for (int p = 0; p < 2; ++p)
                    acc[g][p] = __builtin_amdgcn_mfma_f32_32x32x16_bf16(af,
                        *(const bf16x8*)&wlds[((((g * 8 + 2 * v + p) << 2) + kk) << 9) + (lane << 3)],
                        acc[g][p], 0, 0, 0);
        }
        // kk 4..7: register-resident
#pragma unroll
        for (int kk = 4; kk < 8; ++kk) {
            bf16x8 af = *(const bf16x8*)&hbuf[abase + kk * 16];
#pragma unroll
            for (int g = 0; g < 4; ++g)
#pragma unroll
                for (int p = 0; p < 2; ++p)
                    acc[g][p] = __builtin_amdgcn_mfma_f32_32x32x16_bf16(
                        af, wr[g][p][kk - 4], acc[g][p], 0, 0, 0);
        }
        // kk 8..15: streamed, 2-deep ring (reload slot with kk+2, within-step only)
#pragma unroll
        for (int kk = 8; kk < 16; ++kk) {
            bf16x8 af = *(const bf16x8*)&hbuf[abase + kk * 16];
#pragma unroll
            for (int g = 0; g < 4; ++g)
#pragma unroll
                for (int p = 0; p < 2; ++p)
                    acc[g][p] = __builtin_amdgcn_mfma_f32_32x32x16_bf16(
                        af, sw[kk & 1][2 * g + p], acc[g][p], 0, 0, 0);
            if (kk < 14) {
#pragma unroll
                for (int g = 0; g < 4; ++g)
#pragma unroll
                    for (int p = 0; p < 2; ++p)
                        sw[kk & 1][2 * g + p] = *(const bf16x8*)
                            &WhFrag[(((g * 8 + 2 * v + p) * 16 + kk + 2) << 9) + (lane << 3)];
            }
        }

        __syncthreads();                 // all h reads done
        gates2(acc, c_st, hbuf, rbase, hcol0);
        __syncthreads();                 // h_t visible
    }

    // ---- logits = h @ Wd + bd, register softmax (wave v owns vocab ntile v) ----
    floatx16 accd;
    float p[16];
    float mx[16];
    {
        float bdv = bd[(v << 5) + (lane & 31)];
#pragma unroll
        for (int i = 0; i < 16; ++i) accd[i] = bdv;
#pragma unroll
        for (int kk = 0; kk < 16; ++kk) {
            bf16x8 af = *(const bf16x8*)&hbuf[abase + kk * 16];
            bf16x8 bfd = *(const bf16x8*)(WdFrag + ((((v << 4) + kk) << 6) + lane) * 8);
            accd = __builtin_amdgcn_mfma_f32_32x32x16_bf16(af, bfd, accd, 0, 0, 0);
        }
#pragma unroll
        for (int i = 0; i < 16; ++i) {
            float m = accd[i];
#pragma unroll
            for (int off = 1; off < 32; off <<= 1) m = fmaxf(m, __shfl_xor(m, off, 32));
            mx[i] = m;
        }
        if ((lane & 31) == 0) {
#pragma unroll
            for (int i = 0; i < 16; ++i) red[0][v][(i & 3) + 8 * (i >> 2) + rbase] = mx[i];
        }
    }
    __syncthreads();
    const float L2E = 1.4426950408889634f;
    {
#pragma unroll
        for (int i = 0; i < 16; ++i) {
            int r = (i & 3) + 8 * (i >> 2) + rbase;
            float M = fmaxf(fmaxf(red[0][0][r], red[0][1][r]),
                            fmaxf(red[0][2][r], red[0][3][r]));
            float e = __builtin_amdgcn_exp2f((accd[i] - M) * L2E);
            p[i] = e;
            float s = e;
#pragma unroll
            for (int off = 1; off < 32; off <<= 1) s += __shfl_xor(s, off, 32);
            mx[i] = s;
        }
        if ((lane & 31) == 0) {
#pragma unroll
            for (int i = 0; i < 16; ++i) red[1][v][(i & 3) + 8 * (i >> 2) + rbase] = mx[i];
        }
    }
    __syncthreads();
    {
#pragma unroll
        for (int i = 0; i < 16; ++i) {
            int r = (i & 3) + 8 * (i >> 2) + rbase;
            float tot = red[1][0][r] + red[1][1][r] + red[1][2][r] + red[1][3][r];
            out[(size_t)(r0 + r) * NUM_CHARS + (v << 5) + (lane & 31)] =
                p[i] * __builtin_amdgcn_rcpf(tot);
        }
    }
}

extern "C" void kernel_launch(void* const* d_in, const int* in_sizes, int n_in,
                              void* d_out, int out_size, void* d_ws, size_t ws_size,
                              hipStream_t stream) {
    const int*   inputs = (const int*)d_in[0];
    const float* Wx = (const float*)d_in[1];
    const float* Wh = (const float*)d_in[2];
    const float* b  = (const float*)d_in[3];
    const float* Wd = (const float*)d_in[4];
    const float* bd = (const float*)d_in[5];
    float* out = (float*)d_out;

    unsigned short* WhFrag = (unsigned short*)d_ws;                          // 512 KB
    unsigned short* WxbG   = (unsigned short*)((char*)d_ws + (512 << 10));   // 256 KB
    unsigned short* WdFrag = (unsigned short*)((char*)d_ws + (768 << 10));   //  64 KB

    prep_wh  <<<262144 / 256, 256, 0, stream>>>(Wh, WhFrag);
    prep_wxb4<<<131072 / 256, 256, 0, stream>>>(Wx, b, WxbG);
    prep_wd  <<< 32768 / 256, 256, 0, stream>>>(Wd, WdFrag);
    lstm_main<<<256, 256, 0, stream>>>(inputs, WhFrag, WxbG, WdFrag, bd, out);
}

// Round 7
// 780.227 us; speedup vs baseline: 1.0206x; 1.0206x over previous
//
#include <hip/hip_runtime.h>
#include <stdint.h>

#define NUM_CHARS 128
#define BATCH 8192
#define SEQ 40
#define HIDDEN 256
#define ZDIM 1024   /* 4*HIDDEN */
#define SH 264      /* padded h row stride in ushorts */
#define ROWS 64     /* batch rows per block (2 row-blocks of 32) */
/* 512 threads, 8 waves, 2 waves/SIMD (proven allocation regime).
   Wave w owns hcols [32w,32w+32) for all 4 gates, BOTH row-blocks: acc[4][2].
   B-fragments shared across row-blocks. Wh kk: 0..2 LDS (96KB), 3..15 streamed
   (3-deep window, reload distance 2 groups = 512 cyc). */

typedef __bf16 bf16x8 __attribute__((ext_vector_type(8)));
typedef float floatx16 __attribute__((ext_vector_type(16)));

__device__ __forceinline__ unsigned short f2bf(float f) {
    union { float f; uint32_t u; } v; v.f = f;
    uint32_t u = v.u;
    u += 0x7FFFu + ((u >> 16) & 1u); // RNE
    return (unsigned short)(u >> 16);
}

// WhFrag[ntile(32)][kk(16)][lane(64)][j(8)] bf16 ; element = Wh[k][n],
// k = kk*16 + (lane>>5)*8 + j, n = ntile*32 + (lane&31)
__global__ void prep_wh(const float* __restrict__ Wh, unsigned short* __restrict__ out) {
    int idx = blockIdx.x * blockDim.x + threadIdx.x; // 0..262143
    int j = idx & 7;
    int lane = (idx >> 3) & 63;
    int kk = (idx >> 9) & 15;
    int ntile = idx >> 13;
    int k = kk * 16 + ((lane >> 5) << 3) + j;
    int n = (ntile << 5) + (lane & 31);
    out[idx] = f2bf(Wh[k * ZDIM + n]);
}

// WxbG[vocab(128)][n(256)][g(4)] bf16 = Wx + b, gate-interleaved: one uint2 = 4 gates
__global__ void prep_wxb4(const float* __restrict__ Wx, const float* __restrict__ b,
                          unsigned short* __restrict__ out) {
    int idx = blockIdx.x * blockDim.x + threadIdx.x; // 0..131071
    int v = idx >> 10;
    int n = (idx >> 2) & 255;
    int g = idx & 3;
    out[idx] = f2bf(Wx[v * ZDIM + g * 256 + n] + b[g * 256 + n]);
}

// WdFrag[ntile(4)][kk(16)][lane(64)][j(8)] bf16 ; element = Wd[k][n]
__global__ void prep_wd(const float* __restrict__ Wd, unsigned short* __restrict__ out) {
    int idx = blockIdx.x * blockDim.x + threadIdx.x; // 0..32767
    int j = idx & 7;
    int lane = (idx >> 3) & 63;
    int kk = (idx >> 9) & 15;
    int nt = idx >> 13;
    int k = kk * 16 + ((lane >> 5) << 3) + j;
    int n = (nt << 5) + (lane & 31);
    out[idx] = f2bf(Wd[k * NUM_CHARS + n]);
}

#define ROWI(i) (((i) & 3) + 8 * ((i) >> 2) + rbase)

// gates for one row-block; rowoff = 0 or 32
__device__ __forceinline__ void gates_store(floatx16& a0, floatx16& a1, floatx16& a2,
                                            floatx16& a3, floatx16& c_st,
                                            unsigned short* hb, int rbase, int hcol,
                                            int rowoff) {
    const float L2E = 1.4426950408889634f;
#pragma unroll
    for (int i = 0; i < 16; ++i) {
        float zi = a0[i], zf = a1[i], zg = a2[i], zo = a3[i];
        float si = __builtin_amdgcn_rcpf(1.f + __builtin_amdgcn_exp2f(-zi * L2E));
        float sf = __builtin_amdgcn_rcpf(1.f + __builtin_amdgcn_exp2f(-zf * L2E));
        float so = __builtin_amdgcn_rcpf(1.f + __builtin_amdgcn_exp2f(-zo * L2E));
        float tg = 1.f - 2.f * __builtin_amdgcn_rcpf(1.f + __builtin_amdgcn_exp2f(2.f * L2E * zg));
        float c = sf * c_st[i] + si * tg;
        c_st[i] = c;
        float tc = 1.f - 2.f * __builtin_amdgcn_rcpf(1.f + __builtin_amdgcn_exp2f(2.f * L2E * c));
        hb[(rowoff + ROWI(i)) * SH + hcol] = f2bf(so * tc);
    }
}

// 8 MFMAs per kk group: 4 gates x 2 row-blocks, B shared across row-blocks
#define MFMA8(AFA, AFB, B0, B1, B2, B3)                                                  \
    acc[0][0] = __builtin_amdgcn_mfma_f32_32x32x16_bf16(AFA, B0, acc[0][0], 0, 0, 0);    \
    acc[0][1] = __builtin_amdgcn_mfma_f32_32x32x16_bf16(AFB, B0, acc[0][1], 0, 0, 0);    \
    acc[1][0] = __builtin_amdgcn_mfma_f32_32x32x16_bf16(AFA, B1, acc[1][0], 0, 0, 0);    \
    acc[1][1] = __builtin_amdgcn_mfma_f32_32x32x16_bf16(AFB, B1, acc[1][1], 0, 0, 0);    \
    acc[2][0] = __builtin_amdgcn_mfma_f32_32x32x16_bf16(AFA, B2, acc[2][0], 0, 0, 0);    \
    acc[2][1] = __builtin_amdgcn_mfma_f32_32x32x16_bf16(AFB, B2, acc[2][1], 0, 0, 0);    \
    acc[3][0] = __builtin_amdgcn_mfma_f32_32x32x16_bf16(AFA, B3, acc[3][0], 0, 0, 0);    \
    acc[3][1] = __builtin_amdgcn_mfma_f32_32x32x16_bf16(AFB, B3, acc[3][1], 0, 0, 0);

// LDS-resident kk (0..2): wlds frag index = ntile*3 + kk
#define L_MFMA(KK) {                                                                     \
    bf16x8 afA = *(const bf16x8*)&hbuf[abase + (KK) * 16];                               \
    bf16x8 afB = *(const bf16x8*)&hbuf[abaseB + (KK) * 16];                              \
    bf16x8 b0 = *(const bf16x8*)&wlds[(((0 * 8 + w) * 3 + (KK)) << 9) + (lane << 3)];    \
    bf16x8 b1 = *(const bf16x8*)&wlds[(((1 * 8 + w) * 3 + (KK)) << 9) + (lane << 3)];    \
    bf16x8 b2 = *(const bf16x8*)&wlds[(((2 * 8 + w) * 3 + (KK)) << 9) + (lane << 3)];    \
    bf16x8 b3 = *(const bf16x8*)&wlds[(((3 * 8 + w) * 3 + (KK)) << 9) + (lane << 3)];    \
    MFMA8(afA, afB, b0, b1, b2, b3)                                                      \
}

// streamed kk J (3..15): consume slot (J-3)%3, reload it with kk J+3 (within-step only)
#define S_MFMA(J) {                                                                      \
    bf16x8 afA = *(const bf16x8*)&hbuf[abase + (J) * 16];                                \
    bf16x8 afB = *(const bf16x8*)&hbuf[abaseB + (J) * 16];                               \
    MFMA8(afA, afB, sw[((J) - 3) % 3][0], sw[((J) - 3) % 3][1],                          \
                    sw[((J) - 3) % 3][2], sw[((J) - 3) % 3][3])                          \
    if ((J) + 3 <= 15) {                                                                 \
        sw[((J) - 3) % 3][0] = *(const bf16x8*)(wsb[0] + (((J) + 3) << 9));              \
        sw[((J) - 3) % 3][1] = *(const bf16x8*)(wsb[1] + (((J) + 3) << 9));              \
        sw[((J) - 3) % 3][2] = *(const bf16x8*)(wsb[2] + (((J) + 3) << 9));              \
        sw[((J) - 3) % 3][3] = *(const bf16x8*)(wsb[3] + (((J) + 3) << 9));              \
    }                                                                                    \
}

// ---- main: 128 blocks x 512 threads; block owns 64 batch rows, 1 block/CU ----
__global__ __launch_bounds__(512, 2) void lstm_main(
    const int* __restrict__ inputs, const unsigned short* __restrict__ WhFrag,
    const unsigned short* __restrict__ WxbG, const unsigned short* __restrict__ WdFrag,
    const float* __restrict__ bd, float* __restrict__ out)
{
    __shared__ unsigned short wlds[32 * 3 * 512];     // 96 KB: kk 0..2, all 32 ntiles
    __shared__ unsigned short hbuf[ROWS * SH];        // 33 KB single h buffer (64 rows)
    __shared__ int tok[ROWS * SEQ];                   // 10 KB
    __shared__ float red[2][4][ROWS];                 //  2 KB

    const int tid = threadIdx.x;
    const int w = tid >> 6;        // wave 0..7; gate g's n-tile = g*8 + w
    const int lane = tid & 63;
    const int r0 = blockIdx.x * ROWS;

    // stage tokens (coalesced)
    for (int i = tid; i < ROWS * SEQ; i += 512) tok[i] = inputs[r0 * SEQ + i];
    // stage Wh kk 0..2 into LDS: 96 frags x 1KB; storage frag f = ntile*3 + kk
    for (int c = tid; c < 6144; c += 512) {
        int f = c >> 6, o = c & 63;
        int ntile = f / 3, kkL = f % 3;
        *(bf16x8*)&wlds[(f << 9) + (o << 3)] =
            *(const bf16x8*)&WhFrag[(((ntile << 4) + kkL) << 9) + (o << 3)];
    }

    // per-gate streamed-fragment base pointers, lane offset folded in
    const unsigned short* wsb[4];
#pragma unroll
    for (int g = 0; g < 4; ++g)
        wsb[g] = WhFrag + (((g * 8 + w) * 16) << 9) + (lane << 3);

    const int hcol = (w << 5) + (lane & 31);
    const int rbase = 4 * (lane >> 5);
    const int abase = (lane & 31) * SH + ((lane >> 5) << 3);
    const int abaseB = abase + 32 * SH;

    floatx16 c_st[2];
#pragma unroll
    for (int p = 0; p < 2; ++p)
#pragma unroll
        for (int i = 0; i < 16; ++i) c_st[p][i] = 0.f;

    __syncthreads();  // tok + wlds ready

    // ---- t = 0: h0 = 0, z = Wx[token]+b only ----
    {
        uint2 xa[16], xv[16];
#pragma unroll
        for (int i = 0; i < 16; ++i)
            xa[i] = *(const uint2*)&WxbG[(tok[ROWI(i) * SEQ] << 10) + (hcol << 2)];
#pragma unroll
        for (int i = 0; i < 16; ++i)
            xv[i] = *(const uint2*)&WxbG[(tok[(32 + ROWI(i)) * SEQ] << 10) + (hcol << 2)];
        floatx16 acc[4][2];
#pragma unroll
        for (int i = 0; i < 16; ++i) {
            uint32_t x = xa[i].x, y = xa[i].y;
            acc[0][0][i] = __uint_as_float(x << 16);
            acc[1][0][i] = __uint_as_float(x & 0xFFFF0000u);
            acc[2][0][i] = __uint_as_float(y << 16);
            acc[3][0][i] = __uint_as_float(y & 0xFFFF0000u);
            uint32_t x2 = xv[i].x, y2 = xv[i].y;
            acc[0][1][i] = __uint_as_float(x2 << 16);
            acc[1][1][i] = __uint_as_float(x2 & 0xFFFF0000u);
            acc[2][1][i] = __uint_as_float(y2 << 16);
            acc[3][1][i] = __uint_as_float(y2 & 0xFFFF0000u);
        }
        gates_store(acc[0][0], acc[1][0], acc[2][0], acc[3][0], c_st[0], hbuf, rbase, hcol, 0);
        gates_store(acc[0][1], acc[1][1], acc[2][1], acc[3][1], c_st[1], hbuf, rbase, hcol, 32);
    }
    __syncthreads();

    // ---- t = 1..39 ----
#pragma unroll 1
    for (int t = 1; t < SEQ; ++t) {
        // gather both row-blocks (32 uint2), consumed immediately below
        uint2 xa[16], xv[16];
#pragma unroll
        for (int i = 0; i < 16; ++i)
            xa[i] = *(const uint2*)&WxbG[(tok[ROWI(i) * SEQ + t] << 10) + (hcol << 2)];
#pragma unroll
        for (int i = 0; i < 16; ++i)
            xv[i] = *(const uint2*)&WxbG[(tok[(32 + ROWI(i)) * SEQ + t] << 10) + (hcol << 2)];

        floatx16 acc[4][2];
#pragma unroll
        for (int i = 0; i < 16; ++i) {
            uint32_t x = xa[i].x, y = xa[i].y;
            acc[0][0][i] = __uint_as_float(x << 16);
            acc[1][0][i] = __uint_as_float(x & 0xFFFF0000u);
            acc[2][0][i] = __uint_as_float(y << 16);
            acc[3][0][i] = __uint_as_float(y & 0xFFFF0000u);
            uint32_t x2 = xv[i].x, y2 = xv[i].y;
            acc[0][1][i] = __uint_as_float(x2 << 16);
            acc[1][1][i] = __uint_as_float(x2 & 0xFFFF0000u);
            acc[2][1][i] = __uint_as_float(y2 << 16);
            acc[3][1][i] = __uint_as_float(y2 & 0xFFFF0000u);
        }

        // preload stream window kk 3,4,5 AFTER gather regs die (keeps arch peak <= 128);
        // latency covered by the 3 LDS kk groups (24 MFMA = 768 cyc)
        bf16x8 sw[3][4];
#pragma unroll
        for (int s = 0; s < 3; ++s) {
            sw[s][0] = *(const bf16x8*)(wsb[0] + ((3 + s) << 9));
            sw[s][1] = *(const bf16x8*)(wsb[1] + ((3 + s) << 9));
            sw[s][2] = *(const bf16x8*)(wsb[2] + ((3 + s) << 9));
            sw[s][3] = *(const bf16x8*)(wsb[3] + ((3 + s) << 9));
        }

        L_MFMA(0) L_MFMA(1) L_MFMA(2)
        S_MFMA(3) S_MFMA(4) S_MFMA(5) S_MFMA(6) S_MFMA(7) S_MFMA(8)
        S_MFMA(9) S_MFMA(10) S_MFMA(11) S_MFMA(12) S_MFMA(13) S_MFMA(14) S_MFMA(15)

        __syncthreads();                 // all h reads done
        gates_store(acc[0][0], acc[1][0], acc[2][0], acc[3][0], c_st[0], hbuf, rbase, hcol, 0);
        gates_store(acc[0][1], acc[1][1], acc[2][1], acc[3][1], c_st[1], hbuf, rbase, hcol, 32);
        __syncthreads();                 // h_t visible
    }

    // ---- logits = h @ Wd + bd, register softmax ----
    // wave w: vocab ntile vt = w&3, row-block rb = w>>2
    const int vt = w & 3;
    const int rb = w >> 2;
    const int abaseE = abase + rb * 32 * SH;
    floatx16 accd;
    float p[16];
    float mx[16];
    {
        float bdv = bd[(vt << 5) + (lane & 31)];
#pragma unroll
        for (int i = 0; i < 16; ++i) accd[i] = bdv;
#pragma unroll
        for (int kk = 0; kk < 16; ++kk) {
            bf16x8 af = *(const bf16x8*)&hbuf[abaseE + kk * 16];
            bf16x8 bfd = *(const bf16x8*)(WdFrag + ((((vt << 4) + kk) << 6) + lane) * 8);
            accd = __builtin_amdgcn_mfma_f32_32x32x16_bf16(af, bfd, accd, 0, 0, 0);
        }
#pragma unroll
        for (int i = 0; i < 16; ++i) {
            float m = accd[i];
#pragma unroll
            for (int off = 1; off < 32; off <<= 1) m = fmaxf(m, __shfl_xor(m, off, 32));
            mx[i] = m;
        }
        if ((lane & 31) == 0) {
#pragma unroll
            for (int i = 0; i < 16; ++i) red[0][vt][rb * 32 + ROWI(i)] = mx[i];
        }
    }
    __syncthreads();
    const float L2E = 1.4426950408889634f;
    {
#pragma unroll
        for (int i = 0; i < 16; ++i) {
            int r = rb * 32 + ROWI(i);
            float M = fmaxf(fmaxf(red[0][0][r], red[0][1][r]),
                            fmaxf(red[0][2][r], red[0][3][r]));
            float e = __builtin_amdgcn_exp2f((accd[i] - M) * L2E);
            p[i] = e;
            float s = e;
#pragma unroll
            for (int off = 1; off < 32; off <<= 1) s += __shfl_xor(s, off, 32);
            mx[i] = s;
        }
        if ((lane & 31) == 0) {
#pragma unroll
            for (int i = 0; i < 16; ++i) red[1][vt][rb * 32 + ROWI(i)] = mx[i];
        }
    }
    __syncthreads();
    {
#pragma unroll
        for (int i = 0; i < 16; ++i) {
            int r = rb * 32 + ROWI(i);
            float tot = red[1][0][r] + red[1][1][r] + red[1][2][r] + red[1][3][r];
            out[(size_t)(r0 + r) * NUM_CHARS + (vt << 5) + (lane & 31)] =
                p[i] * __builtin_amdgcn_rcpf(tot);
        }
    }
}

extern "C" void kernel_launch(void* const* d_in, const int* in_sizes, int n_in,
                              void* d_out, int out_size, void* d_ws, size_t ws_size,
                              hipStream_t stream) {
    const int*   inputs = (const int*)d_in[0];
    const float* Wx = (const float*)d_in[1];
    const float* Wh = (const float*)d_in[2];
    const float* b  = (const float*)d_in[3];
    const float* Wd = (const float*)d_in[4];
    const float* bd = (const float*)d_in[5];
    float* out = (float*)d_out;

    unsigned short* WhFrag = (unsigned short*)d_ws;                          // 512 KB
    unsigned short* WxbG   = (unsigned short*)((char*)d_ws + (512 << 10));   // 256 KB
    unsigned short* WdFrag = (unsigned short*)((char*)d_ws + (768 << 10));   //  64 KB

    prep_wh  <<<262144 / 256, 256, 0, stream>>>(Wh, WhFrag);
    prep_wxb4<<<131072 / 256, 256, 0, stream>>>(Wx, b, WxbG);
    prep_wd  <<< 32768 / 256, 256, 0, stream>>>(Wd, WdFrag);
    lstm_main<<<BATCH / ROWS, 512, 0, stream>>>(inputs, WhFrag, WxbG, WdFrag, bd, out);
}

// Round 8
// 461.671 us; speedup vs baseline: 1.7248x; 1.6900x over previous
//
#include <hip/hip_runtime.h>
#include <stdint.h>

#define NUM_CHARS 128
#define BATCH 8192
#define SEQ 40
#define HIDDEN 256
#define ZDIM 1024   /* 4*HIDDEN */
#define SH 264      /* padded h row stride in ushorts */
/* 512 thr / 8 waves / 32 rows / 1 block/CU (proven regime; arch regs <= 128).
   Wh kk: 0..2 LDS (96 KB), 3 register (16 regs), 4..15 streamed (2-slot ring, within-step).
   Double h buffer -> ONE raw barrier per step; xb gather prefetched across the barrier. */

typedef __bf16 bf16x8 __attribute__((ext_vector_type(8)));
typedef float floatx16 __attribute__((ext_vector_type(16)));

__device__ __forceinline__ unsigned short f2bf(float f) {
    union { float f; uint32_t u; } v; v.f = f;
    uint32_t u = v.u;
    u += 0x7FFFu + ((u >> 16) & 1u); // RNE
    return (unsigned short)(u >> 16);
}

// WhFrag[ntile(32)][kk(16)][lane(64)][j(8)] bf16 ; element = Wh[k][n],
// k = kk*16 + (lane>>5)*8 + j, n = ntile*32 + (lane&31)
__global__ void prep_wh(const float* __restrict__ Wh, unsigned short* __restrict__ out) {
    int idx = blockIdx.x * blockDim.x + threadIdx.x; // 0..262143
    int j = idx & 7;
    int lane = (idx >> 3) & 63;
    int kk = (idx >> 9) & 15;
    int ntile = idx >> 13;
    int k = kk * 16 + ((lane >> 5) << 3) + j;
    int n = (ntile << 5) + (lane & 31);
    out[idx] = f2bf(Wh[k * ZDIM + n]);
}

// WxbG[vocab(128)][n(256)][g(4)] bf16 = Wx + b, gate-interleaved: one uint2 = 4 gates
__global__ void prep_wxb4(const float* __restrict__ Wx, const float* __restrict__ b,
                          unsigned short* __restrict__ out) {
    int idx = blockIdx.x * blockDim.x + threadIdx.x; // 0..131071
    int v = idx >> 10;
    int n = (idx >> 2) & 255;
    int g = idx & 3;
    out[idx] = f2bf(Wx[v * ZDIM + g * 256 + n] + b[g * 256 + n]);
}

// WdFrag[ntile(4)][kk(16)][lane(64)][j(8)] bf16 ; element = Wd[k][n]
__global__ void prep_wd(const float* __restrict__ Wd, unsigned short* __restrict__ out) {
    int idx = blockIdx.x * blockDim.x + threadIdx.x; // 0..32767
    int j = idx & 7;
    int lane = (idx >> 3) & 63;
    int kk = (idx >> 9) & 15;
    int nt = idx >> 13;
    int k = kk * 16 + ((lane >> 5) << 3) + j;
    int n = (nt << 5) + (lane & 31);
    out[idx] = f2bf(Wd[k * NUM_CHARS + n]);
}

#define ROWI(i) (((i) & 3) + 8 * ((i) >> 2) + rbase)

__device__ __forceinline__ void gates_store(floatx16 (&acc)[4], floatx16& c_st,
                                            unsigned short* hn, int rbase, int hcol) {
    const float L2E = 1.4426950408889634f;
#pragma unroll
    for (int i = 0; i < 16; ++i) {
        float zi = acc[0][i], zf = acc[1][i], zg = acc[2][i], zo = acc[3][i];
        float si = __builtin_amdgcn_rcpf(1.f + __builtin_amdgcn_exp2f(-zi * L2E));
        float sf = __builtin_amdgcn_rcpf(1.f + __builtin_amdgcn_exp2f(-zf * L2E));
        float so = __builtin_amdgcn_rcpf(1.f + __builtin_amdgcn_exp2f(-zo * L2E));
        float tg = 1.f - 2.f * __builtin_amdgcn_rcpf(1.f + __builtin_amdgcn_exp2f(2.f * L2E * zg));
        float c = sf * c_st[i] + si * tg;
        c_st[i] = c;
        float tc = 1.f - 2.f * __builtin_amdgcn_rcpf(1.f + __builtin_amdgcn_exp2f(2.f * L2E * c));
        hn[ROWI(i) * SH + hcol] = f2bf(so * tc);
    }
}

#define MFMA4(AF, B0, B1, B2, B3)                                                   \
    acc[0] = __builtin_amdgcn_mfma_f32_32x32x16_bf16(AF, B0, acc[0], 0, 0, 0);      \
    acc[1] = __builtin_amdgcn_mfma_f32_32x32x16_bf16(AF, B1, acc[1], 0, 0, 0);      \
    acc[2] = __builtin_amdgcn_mfma_f32_32x32x16_bf16(AF, B2, acc[2], 0, 0, 0);      \
    acc[3] = __builtin_amdgcn_mfma_f32_32x32x16_bf16(AF, B3, acc[3], 0, 0, 0);

// LDS-resident kk (0..2): wlds frag index = ntile*3 + kk, ntile = g*8+w
#define L_MFMA(KK) {                                                                 \
    bf16x8 af = *(const bf16x8*)&hb[abase + (KK) * 16];                              \
    bf16x8 b0 = *(const bf16x8*)&wlds[(((0 * 8 + w) * 3 + (KK)) << 9) + (lane << 3)];\
    bf16x8 b1 = *(const bf16x8*)&wlds[(((1 * 8 + w) * 3 + (KK)) << 9) + (lane << 3)];\
    bf16x8 b2 = *(const bf16x8*)&wlds[(((2 * 8 + w) * 3 + (KK)) << 9) + (lane << 3)];\
    bf16x8 b3 = *(const bf16x8*)&wlds[(((3 * 8 + w) * 3 + (KK)) << 9) + (lane << 3)];\
    MFMA4(af, b0, b1, b2, b3)                                                        \
}

// register-resident kk 3
#define R_MFMA3() {                                                                  \
    bf16x8 af = *(const bf16x8*)&hb[abase + 3 * 16];                                 \
    MFMA4(af, wr[0], wr[1], wr[2], wr[3])                                            \
}

// streamed kk J (4..15): consume slot (J-4)&1, reload it with kk J+2 for J<=13
#define S_MFMA(J) {                                                                  \
    bf16x8 af = *(const bf16x8*)&hb[abase + (J) * 16];                               \
    MFMA4(af, sw[((J) - 4) & 1][0], sw[((J) - 4) & 1][1],                            \
              sw[((J) - 4) & 1][2], sw[((J) - 4) & 1][3])                            \
    if ((J) <= 13) {                                                                 \
        sw[((J) - 4) & 1][0] = *(const bf16x8*)(wsb[0] + (((J) + 2) << 9));          \
        sw[((J) - 4) & 1][1] = *(const bf16x8*)(wsb[1] + (((J) + 2) << 9));          \
        sw[((J) - 4) & 1][2] = *(const bf16x8*)(wsb[2] + (((J) + 2) << 9));          \
        sw[((J) - 4) & 1][3] = *(const bf16x8*)(wsb[3] + (((J) + 2) << 9));          \
    }                                                                                \
}

// raw barrier with fences: LDS writes drained, schedule pinned, vmem stays in flight
#define PHASE_BARRIER() {                                                            \
    asm volatile("s_waitcnt lgkmcnt(0)" ::: "memory");                               \
    __builtin_amdgcn_sched_barrier(0);                                               \
    __builtin_amdgcn_s_barrier();                                                    \
    __builtin_amdgcn_sched_barrier(0);                                               \
}

// ---- main: 256 blocks x 512 threads; block owns 32 batch rows, 1 block/CU ----
__global__ __launch_bounds__(512) void lstm_main(
    const int* __restrict__ inputs, const unsigned short* __restrict__ WhFrag,
    const unsigned short* __restrict__ WxbG, const unsigned short* __restrict__ WdFrag,
    const float* __restrict__ bd, float* __restrict__ out)
{
    __shared__ unsigned short wlds[32 * 3 * 512];     // 96 KB: kk 0..2, all 32 ntiles
    __shared__ unsigned short hbuf[2][32 * SH];       // 33 KB double h buffer
    __shared__ int tok[32 * SEQ];                     //  5 KB
    __shared__ float red[2][4][32];                   //  1 KB

    const int tid = threadIdx.x;
    const int w = tid >> 6;        // wave 0..7; gate g's n-tile = g*8 + w
    const int lane = tid & 63;
    const int r0 = blockIdx.x * 32;

    // stage tokens (coalesced)
    for (int i = tid; i < 32 * SEQ; i += 512) tok[i] = inputs[r0 * SEQ + i];
    // stage Wh kk 0..2 into LDS: 96 frags x 1KB; storage frag f = ntile*3 + kk
    for (int c = tid; c < 6144; c += 512) {
        int f = c >> 6, o = c & 63;
        int ntile = f / 3, kkL = f % 3;
        *(bf16x8*)&wlds[(f << 9) + (o << 3)] =
            *(const bf16x8*)&WhFrag[(((ntile << 4) + kkL) << 9) + (o << 3)];
    }

    // per-gate streamed-fragment base pointers, lane offset folded in
    const unsigned short* wsb[4];
#pragma unroll
    for (int g = 0; g < 4; ++g)
        wsb[g] = WhFrag + (((g * 8 + w) * 16) << 9) + (lane << 3);

    // register-resident kk 3 (16 arch regs)
    bf16x8 wr[4];
#pragma unroll
    for (int g = 0; g < 4; ++g)
        wr[g] = *(const bf16x8*)(wsb[g] + (3 << 9));

    const int hcol = (w << 5) + (lane & 31);
    const int rbase = 4 * (lane >> 5);
    const int abase = (lane & 31) * SH + ((lane >> 5) << 3);

    floatx16 c_st;
#pragma unroll
    for (int i = 0; i < 16; ++i) c_st[i] = 0.f;

    __syncthreads();  // tok + wlds ready (full sync, prologue only)

    uint2 xb[16];  // gather prefetch (live only gates->next-top)
#pragma unroll
    for (int i = 0; i < 16; ++i)
        xb[i] = *(const uint2*)&WxbG[(tok[ROWI(i) * SEQ] << 10) + (hcol << 2)];

    unsigned short* hcur = &hbuf[0][0];
    unsigned short* hnext = &hbuf[1][0];

    // ---- t = 0: h0 = 0, z = Wx[token]+b only ----
    {
        floatx16 acc[4];
#pragma unroll
        for (int i = 0; i < 16; ++i) {
            uint32_t x = xb[i].x, y = xb[i].y;
            acc[0][i] = __uint_as_float(x << 16);
            acc[1][i] = __uint_as_float(x & 0xFFFF0000u);
            acc[2][i] = __uint_as_float(y << 16);
            acc[3][i] = __uint_as_float(y & 0xFFFF0000u);
        }
        // prefetch gather for t = 1 (stays in flight across the raw barrier)
#pragma unroll
        for (int i = 0; i < 16; ++i)
            xb[i] = *(const uint2*)&WxbG[(tok[ROWI(i) * SEQ + 1] << 10) + (hcol << 2)];
        gates_store(acc, c_st, hcur, rbase, hcol);  // h_0 -> hbuf[0]
    }
    PHASE_BARRIER();

    // ---- t = 1..39: read hcur, write hnext, ONE barrier per step ----
#pragma unroll 1
    for (int t = 1; t < SEQ; ++t) {
        const unsigned short* hb = hcur;

        // acc init from prefetched gather (xb dies here)
        floatx16 acc[4];
#pragma unroll
        for (int i = 0; i < 16; ++i) {
            uint32_t x = xb[i].x, y = xb[i].y;
            acc[0][i] = __uint_as_float(x << 16);
            acc[1][i] = __uint_as_float(x & 0xFFFF0000u);
            acc[2][i] = __uint_as_float(y << 16);
            acc[3][i] = __uint_as_float(y & 0xFFFF0000u);
        }
        // preload stream window kk 4,5 (latency covered by L0..L2 + R3 = 16 MFMA)
        bf16x8 sw[2][4];
#pragma unroll
        for (int s = 0; s < 2; ++s) {
            sw[s][0] = *(const bf16x8*)(wsb[0] + ((4 + s) << 9));
            sw[s][1] = *(const bf16x8*)(wsb[1] + ((4 + s) << 9));
            sw[s][2] = *(const bf16x8*)(wsb[2] + ((4 + s) << 9));
            sw[s][3] = *(const bf16x8*)(wsb[3] + ((4 + s) << 9));
        }

        L_MFMA(0) L_MFMA(1) L_MFMA(2) R_MFMA3()
        S_MFMA(4) S_MFMA(5) S_MFMA(6) S_MFMA(7) S_MFMA(8) S_MFMA(9)
        S_MFMA(10) S_MFMA(11) S_MFMA(12) S_MFMA(13) S_MFMA(14) S_MFMA(15)

        // issue gather for t+1 — flies through gates + barrier (raw barrier keeps it)
        int tn = (t + 1 < SEQ) ? t + 1 : SEQ - 1;
#pragma unroll
        for (int i = 0; i < 16; ++i)
            xb[i] = *(const uint2*)&WxbG[(tok[ROWI(i) * SEQ + tn] << 10) + (hcol << 2)];

        gates_store(acc, c_st, hnext, rbase, hcol);  // h_t -> other buffer

        PHASE_BARRIER();                 // h_t visible; readers of hb finished pre-barrier
        unsigned short* tmp = hcur; hcur = hnext; hnext = tmp;
    }

    // ---- logits = h @ Wd + bd, register softmax (waves 0..3, vocab ntile = w) ----
    floatx16 accd;
    float p[16];
    float mx[16];
    const unsigned short* hb = hcur;  // h_39
    if (w < 4) {
        float bdv = bd[(w << 5) + (lane & 31)];
#pragma unroll
        for (int i = 0; i < 16; ++i) accd[i] = bdv;
#pragma unroll
        for (int kk = 0; kk < 16; ++kk) {
            bf16x8 af = *(const bf16x8*)&hb[abase + kk * 16];
            bf16x8 bfd = *(const bf16x8*)(WdFrag + ((((w << 4) + kk) << 6) + lane) * 8);
            accd = __builtin_amdgcn_mfma_f32_32x32x16_bf16(af, bfd, accd, 0, 0, 0);
        }
#pragma unroll
        for (int i = 0; i < 16; ++i) {
            float m = accd[i];
#pragma unroll
            for (int off = 1; off < 32; off <<= 1) m = fmaxf(m, __shfl_xor(m, off, 32));
            mx[i] = m;
        }
        if ((lane & 31) == 0) {
#pragma unroll
            for (int i = 0; i < 16; ++i) red[0][w][ROWI(i)] = mx[i];
        }
    }
    __syncthreads();
    const float L2E = 1.4426950408889634f;
    if (w < 4) {
#pragma unroll
        for (int i = 0; i < 16; ++i) {
            int r = ROWI(i);
            float M = fmaxf(fmaxf(red[0][0][r], red[0][1][r]),
                            fmaxf(red[0][2][r], red[0][3][r]));
            float e = __builtin_amdgcn_exp2f((accd[i] - M) * L2E);
            p[i] = e;
            float s = e;
#pragma unroll
            for (int off = 1; off < 32; off <<= 1) s += __shfl_xor(s, off, 32);
            mx[i] = s;
        }
        if ((lane & 31) == 0) {
#pragma unroll
            for (int i = 0; i < 16; ++i) red[1][w][ROWI(i)] = mx[i];
        }
    }
    __syncthreads();
    if (w < 4) {
#pragma unroll
        for (int i = 0; i < 16; ++i) {
            int r = ROWI(i);
            float tot = red[1][0][r] + red[1][1][r] + red[1][2][r] + red[1][3][r];
            out[(size_t)(r0 + r) * NUM_CHARS + (w << 5) + (lane & 31)] =
                p[i] * __builtin_amdgcn_rcpf(tot);
        }
    }
}

extern "C" void kernel_launch(void* const* d_in, const int* in_sizes, int n_in,
                              void* d_out, int out_size, void* d_ws, size_t ws_size,
                              hipStream_t stream) {
    const int*   inputs = (const int*)d_in[0];
    const float* Wx = (const float*)d_in[1];
    const float* Wh = (const float*)d_in[2];
    const float* b  = (const float*)d_in[3];
    const float* Wd = (const float*)d_in[4];
    const float* bd = (const float*)d_in[5];
    float* out = (float*)d_out;

    unsigned short* WhFrag = (unsigned short*)d_ws;                          // 512 KB
    unsigned short* WxbG   = (unsigned short*)((char*)d_ws + (512 << 10));   // 256 KB
    unsigned short* WdFrag = (unsigned short*)((char*)d_ws + (768 << 10));   //  64 KB

    prep_wh  <<<262144 / 256, 256, 0, stream>>>(Wh, WhFrag);
    prep_wxb4<<<131072 / 256, 256, 0, stream>>>(Wx, b, WxbG);
    prep_wd  <<< 32768 / 256, 256, 0, stream>>>(Wd, WdFrag);
    lstm_main<<<256, 512, 0, stream>>>(inputs, WhFrag, WxbG, WdFrag, bd, out);
}